// Round 6
// baseline (152.792 us; speedup 1.0000x reference)
//
#include <hip/hip_runtime.h>
#include <cstdint>
#include <cstddef>

// SoftTree: out[b,o] = sum_l ((x@pw[o])[b,l] + pb[o,l]) * p[b,l]
// B=4096, I=512, O=64, L=256, GATES=255, depth 8.
#define GATES 255

typedef __attribute__((ext_vector_type(8))) short bf16x8;   // 8 bf16 = 4 VGPR
typedef __attribute__((ext_vector_type(4))) float f32x4;

__device__ __forceinline__ short f2bf(float f) {
  union { float f; uint32_t u; } c; c.f = f;
  uint32_t r = c.u + 0x7FFFu + ((c.u >> 16) & 1u);   // RNE
  return (short)(r >> 16);
}

#define GLOAD16(gp, lp) __builtin_amdgcn_global_load_lds( \
    (const __attribute__((address_space(1))) uint32_t*)(gp), \
    (__attribute__((address_space(3))) uint32_t*)(lp), 16, 0, 0)

// ---------------- merged prep: x->bf16 | gw transpose | pw transpose ---------
__global__ __launch_bounds__(256) void k_prep(const float* __restrict__ x,
                                              short* __restrict__ xb,
                                              const float* __restrict__ gw,
                                              short* __restrict__ gwt,
                                              const float* __restrict__ pw,
                                              short* __restrict__ pwt) {
  __shared__ short t[64][65];
  const int bx = blockIdx.x;
  const int tid = threadIdx.x;

  if (bx < 2048) {                      // ---- convert x ----
    const int i = bx * 256 + tid;       // 524288 float4s
    const float4 v = ((const float4*)x)[i];
    short4 s;
    s.x = f2bf(v.x); s.y = f2bf(v.y); s.z = f2bf(v.z); s.w = f2bf(v.w);
    ((short4*)xb)[i] = s;
    return;
  }

  const int c = tid & 63, r0 = tid >> 6;

  if (bx < 2080) {                      // ---- gw transpose ----
    const int b2 = bx - 2048;           // 8 iblk * 4 gblk
    const int ib = b2 >> 2, gb = b2 & 3;
    const int i0 = ib << 6, g0 = gb << 6;
#pragma unroll
    for (int rr = 0; rr < 16; ++rr) {
      const int i = rr * 4 + r0;
      const int g = g0 + c;
      t[i][c] = (g < GATES) ? f2bf(gw[(size_t)(i0 + i) * GATES + g]) : (short)0;
    }
    __syncthreads();
#pragma unroll
    for (int rr = 0; rr < 16; ++rr) {
      const int gg = rr * 4 + r0;
      gwt[(size_t)(g0 + gg) * 512 + i0 + c] = t[c][gg];
    }
    return;
  }

  // ---- pw transpose ----
  const int b2 = bx - 2080;             // 64 o * 8 iblk * 4 lblk
  const int o = b2 >> 5;
  const int ib = (b2 >> 2) & 7;
  const int lb = b2 & 3;
  const int i0 = ib << 6, l0 = lb << 6;
  const float* src = pw + ((size_t)o * 512 + i0) * 256 + l0;
#pragma unroll
  for (int rr = 0; rr < 16; ++rr) {
    const int i = rr * 4 + r0;
    t[i][c] = f2bf(src[(size_t)i * 256 + c]);            // coalesced over l
  }
  __syncthreads();
  short* dst = pwt + ((size_t)o * 256 + l0) * 512 + i0;
#pragma unroll
  for (int rr = 0; rr < 16; ++rr) {
    const int ll = rr * 4 + r0;
    dst[(size_t)ll * 512 + c] = t[c][ll];                // coalesced over i
  }
}

// ---------------- gating via MFMA + fused sigmoid + leaf products ------------
__global__ __launch_bounds__(256, 1) void k_gate(const short* __restrict__ xb,
                                                 const short* __restrict__ gwt,
                                                 const float* __restrict__ gb,
                                                 float* __restrict__ p) {
  __shared__ short a_lds[64 * 64];     // 8KB
  __shared__ short b_lds[256 * 64];    // 32KB
  __shared__ float gs[64][260];        // sigmoid gates, 65KB

  const int b0 = blockIdx.x << 6;      // 64 blocks
  const int tid = threadIdx.x;
  const int lane = tid & 63;
  const int w = tid >> 6;
  const int wr = w >> 1, wc = w & 1;   // wave tile 32x128

  const short* Ab = xb + (size_t)b0 * 512;

  f32x4 acc[2][8];
#pragma unroll
  for (int mf = 0; mf < 2; ++mf)
#pragma unroll
    for (int nf = 0; nf < 8; ++nf) {
      acc[mf][nf][0] = 0.f; acc[mf][nf][1] = 0.f;
      acc[mf][nf][2] = 0.f; acc[mf][nf][3] = 0.f;
    }

  for (int s = 0; s < 8; ++s) {
    const int i0 = s << 6;
    __syncthreads();
#pragma unroll
    for (int sw = 0; sw < 2; ++sw) {   // A: 512 x 16B chunks
      const int chunk = sw * 256 + tid;
      const int r = chunk >> 3, c = (chunk & 7) << 3;
      GLOAD16(Ab + (size_t)r * 512 + i0 + c, a_lds + chunk * 8);
    }
#pragma unroll
    for (int sw = 0; sw < 8; ++sw) {   // B: 2048 x 16B chunks
      const int chunk = sw * 256 + tid;
      const int r = chunk >> 3, c = (chunk & 7) << 3;
      GLOAD16(gwt + (size_t)r * 512 + i0 + c, b_lds + chunk * 8);
    }
    __syncthreads();
#pragma unroll
    for (int kk = 0; kk < 2; ++kk) {
      const int kb = (kk << 5) + ((lane >> 4) << 3);
      bf16x8 af[2], bfr[8];
#pragma unroll
      for (int mf = 0; mf < 2; ++mf) {
        const int row = (wr << 5) + (mf << 4) + (lane & 15);
        af[mf] = *(const bf16x8*)(a_lds + row * 64 + kb);
      }
#pragma unroll
      for (int nf = 0; nf < 8; ++nf) {
        const int row = (wc << 7) + (nf << 4) + (lane & 15);
        bfr[nf] = *(const bf16x8*)(b_lds + row * 64 + kb);
      }
#pragma unroll
      for (int mf = 0; mf < 2; ++mf)
#pragma unroll
        for (int nf = 0; nf < 8; ++nf)
          acc[mf][nf] = __builtin_amdgcn_mfma_f32_16x16x32_bf16(
              af[mf], bfr[nf], acc[mf][nf], 0, 0, 0);
    }
  }

  // sigmoid(logit + gb) -> gs[b_local][g]
  const int grp = lane >> 4, lcol = lane & 15;
#pragma unroll
  for (int nf = 0; nf < 8; ++nf) {
    const int g = (wc << 7) + (nf << 4) + lcol;
    const float bias = (g < GATES) ? gb[g] : 0.f;
#pragma unroll
    for (int mf = 0; mf < 2; ++mf)
#pragma unroll
      for (int rg = 0; rg < 4; ++rg) {
        const int bl = (wr << 5) + (mf << 4) + (grp << 2) + rg;
        const float z = acc[mf][nf][rg] + bias;
        gs[bl][g] = 1.f / (1.f + __expf(-z));
      }
  }
  __syncthreads();

  // leaf probs: thread handles leaf l=tid for all 64 rows
  const int l = tid;
  for (int r = 0; r < 64; ++r) {
    float prob = 1.f;
    int index = 1;
#pragma unroll
    for (int j = 0; j < 8; ++j) {
      const int bit = (l >> (7 - j)) & 1;
      const float gg = gs[r][index - 1];
      prob *= bit ? (1.f - gg) : gg;
      index = 2 * index + bit;
    }
    p[(size_t)(b0 + r) * 256 + l] = prob;
  }
}

// ---------------- main fused GEMM, 8-phase schedule (T3+T4+T2+T5) -----------
// BM=256, BN=256(=L), BK=64 (2 K-halves of 32); 8 waves 2Mx4N; wave 128x64.
// T1 XCD-chunked work remap (m204): HW round-robins blockIdx->XCD (bid%8);
// giving each XCD a contiguous o-band makes its 32 resident blocks
// = 2 o-values x 16 bm-tiles -> B-panels (256KB/o), xb (4MB) and p-slices
// stay L2-hot instead of streaming 768MB from L3 (the R3-R5 plateau).
__global__ __launch_bounds__(512, 1) void k_main(const short* __restrict__ xb,
                                                 const short* __restrict__ pwt,
                                                 const float* __restrict__ p,
                                                 const float* __restrict__ pb,
                                                 float* __restrict__ out) {
  __shared__ short lds[65536];        // [buf][mat][kh][256*32] = 128KB

  const int bx = blockIdx.x;          // 1024 blocks
  const int wid = (bx & 7) * 128 + (bx >> 3);   // XCD-chunked work id
  const int o = wid >> 4;
  const int bm0 = (wid & 15) << 8;
  const int tid = threadIdx.x;
  const int lane = tid & 63;
  const int w = tid >> 6;             // 0..7
  const int wr = w >> 2;              // 0..1  (m half)
  const int wc = w & 3;               // 0..3  (n quarter)

  const short* Ab = xb + (size_t)bm0 * 512;
  const short* Bb = pwt + (size_t)o * (256 * 512);

  f32x4 acc[8][4];
#pragma unroll
  for (int mf = 0; mf < 8; ++mf)
#pragma unroll
    for (int nf = 0; nf < 4; ++nf) {
      acc[mf][nf][0] = 0.f; acc[mf][nf][1] = 0.f;
      acc[mf][nf][2] = 0.f; acc[mf][nf][3] = 0.f;
    }

  // half s of tile t: s = {A-kh0, B-kh0, A-kh1, B-kh1}; 2 loads/thread.
  // LDS pos p in row receives global 16B-block p ^ ((row>>1)&3).
  auto stageHalf = [&](int buf, int t, int s) {
    const int mat = s & 1, kh = s >> 1;
    const short* base = mat ? Bb : Ab;
    const int koff = (t << 6) + (kh << 5);
    short* dst = &lds[((buf * 2 + mat) * 2 + kh) * 8192];
#pragma unroll
    for (int j = 0; j < 2; ++j) {
      const int c = j * 512 + tid;
      const int row = c >> 2, pp = c & 3;
      const int gblk = pp ^ ((row >> 1) & 3);
      GLOAD16(base + (size_t)row * 512 + koff + (gblk << 3), dst + c * 8);
    }
  };

  auto readB4 = [&](int buf, int kh, bf16x8 bfr[4]) {
    const short* src = &lds[((buf * 2 + 1) * 2 + kh) * 8192];
#pragma unroll
    for (int nf = 0; nf < 4; ++nf) {
      const int row = (wc << 6) + (nf << 4) + (lane & 15);
      const int blk = (lane >> 4) ^ ((row >> 1) & 3);
      bfr[nf] = *(const bf16x8*)(src + row * 32 + (blk << 3));
    }
  };
  auto readA4 = [&](int buf, int kh, int mh, bf16x8 af[4]) {
    const short* src = &lds[((buf * 2 + 0) * 2 + kh) * 8192];
#pragma unroll
    for (int mf = 0; mf < 4; ++mf) {
      const int row = (wr << 7) + (((mh << 2) + mf) << 4) + (lane & 15);
      const int blk = (lane >> 4) ^ ((row >> 1) & 3);
      af[mf] = *(const bf16x8*)(src + row * 32 + (blk << 3));
    }
  };
  auto mfma16 = [&](int mh, const bf16x8 af[4], const bf16x8 bfr[4]) {
    __builtin_amdgcn_s_setprio(1);
#pragma unroll
    for (int mf = 0; mf < 4; ++mf)
#pragma unroll
      for (int nf = 0; nf < 4; ++nf)
        acc[(mh << 2) + mf][nf] = __builtin_amdgcn_mfma_f32_16x16x32_bf16(
            af[mf], bfr[nf], acc[(mh << 2) + mf][nf], 0, 0, 0);
    __builtin_amdgcn_s_setprio(0);
  };

  bf16x8 af[4], bfr[4];

  // prologue: stage all 4 halves of tile 0, drain kh0's (oldest 4), barrier
  stageHalf(0, 0, 0); stageHalf(0, 0, 1); stageHalf(0, 0, 2); stageHalf(0, 0, 3);
  asm volatile("s_waitcnt vmcnt(4)" ::: "memory");
  __builtin_amdgcn_s_barrier();

  for (int t = 0; t < 7; ++t) {
    const int buf = t & 1;
    // ---- kh0, phase 0 (mh0) ----
    readB4(buf, 0, bfr); readA4(buf, 0, 0, af);
    stageHalf(buf ^ 1, t + 1, 0);
    __builtin_amdgcn_s_barrier();
    mfma16(0, af, bfr);
    __builtin_amdgcn_s_barrier();
    // ---- kh0, phase 1 (mh1) ----
    readA4(buf, 0, 1, af);
    stageHalf(buf ^ 1, t + 1, 1);
    __builtin_amdgcn_s_barrier();
    mfma16(1, af, bfr);
    asm volatile("s_waitcnt vmcnt(4)" ::: "memory");   // drain prev-tile kh1
    __builtin_amdgcn_s_barrier();
    // ---- kh1, phase 2 (mh0) ----
    readB4(buf, 1, bfr); readA4(buf, 1, 0, af);
    stageHalf(buf ^ 1, t + 1, 2);
    __builtin_amdgcn_s_barrier();
    mfma16(0, af, bfr);
    __builtin_amdgcn_s_barrier();
    // ---- kh1, phase 3 (mh1) ----
    readA4(buf, 1, 1, af);
    stageHalf(buf ^ 1, t + 1, 3);
    __builtin_amdgcn_s_barrier();
    mfma16(1, af, bfr);
    asm volatile("s_waitcnt vmcnt(4)" ::: "memory");   // drain next-tile kh0
    __builtin_amdgcn_s_barrier();
  }
  // ---- tile 7 (buf=1), no staging ----
  readB4(1, 0, bfr); readA4(1, 0, 0, af);
  __builtin_amdgcn_s_barrier();
  mfma16(0, af, bfr);
  __builtin_amdgcn_s_barrier();
  readA4(1, 0, 1, af);
  __builtin_amdgcn_s_barrier();
  mfma16(1, af, bfr);
  asm volatile("s_waitcnt vmcnt(0)" ::: "memory");     // drain tile-7 kh1
  __builtin_amdgcn_s_barrier();
  readB4(1, 1, bfr); readA4(1, 1, 0, af);
  __builtin_amdgcn_s_barrier();
  mfma16(0, af, bfr);
  __builtin_amdgcn_s_barrier();
  readA4(1, 1, 1, af);
  __builtin_amdgcn_s_barrier();
  mfma16(1, af, bfr);

  __syncthreads();                    // full drain before LDS reuse

  // epilogue: D lane map (m89): col(l)=lane&15, row(b)=(lane>>4)*4+reg
  float* red = (float*)&lds[0];       // red[4][256] overlay, 4KB
  const int grp = lane >> 4;
  const int lcol = lane & 15;
  float pbv[4];
#pragma unroll
  for (int nf = 0; nf < 4; ++nf)
    pbv[nf] = pb[(size_t)o * 256 + (wc << 6) + (nf << 4) + lcol];
#pragma unroll
  for (int mf = 0; mf < 8; ++mf) {
#pragma unroll
    for (int rg = 0; rg < 4; ++rg) {
      const int bl = (wr << 7) + (mf << 4) + (grp << 2) + rg;  // b within tile
      const int b = bm0 + bl;
      float v = 0.f;
#pragma unroll
      for (int nf = 0; nf < 4; ++nf) {
        const int l = (wc << 6) + (nf << 4) + lcol;
        v += (acc[mf][nf][rg] + pbv[nf]) * p[(size_t)b * 256 + l];
      }
      v += __shfl_xor(v, 1);
      v += __shfl_xor(v, 2);
      v += __shfl_xor(v, 4);
      v += __shfl_xor(v, 8);
      if (lcol == 0) red[wc * 256 + bl] = v;
    }
  }
  __syncthreads();
  if (tid < 256) {
    out[(size_t)(bm0 + tid) * 64 + o] =
        red[tid] + red[256 + tid] + red[512 + tid] + red[768 + tid];
  }
}

extern "C" void kernel_launch(void* const* d_in, const int* in_sizes, int n_in,
                              void* d_out, int out_size, void* d_ws, size_t ws_size,
                              hipStream_t stream) {
  (void)in_sizes; (void)n_in; (void)out_size; (void)ws_size;
  const float* x  = (const float*)d_in[0];
  const float* gw = (const float*)d_in[1];
  const float* gb = (const float*)d_in[2];
  const float* pw = (const float*)d_in[3];
  const float* pb = (const float*)d_in[4];
  // d_in[5] leaf_idx / d_in[6] leaf_bit: tree is deterministic, recomputed in-kernel.
  float* out = (float*)d_out;

  char* ws = (char*)d_ws;
  short* xbuf = (short*)(ws);                              // 4 MB bf16 x
  short* gwt  = (short*)(ws + ((size_t)4 << 20));          // 256 KB bf16 gw_t
  short* pwt  = (short*)(ws + ((size_t)4 << 20) + (256 << 10));  // 16 MB bf16 pw_t
  float* p    = (float*)(ws + ((size_t)20 << 20) + (256 << 10)); // 4 MB leaf probs

  k_prep<<<4128, 256, 0, stream>>>(x, xbuf, gw, gwt, pw, pwt);
  k_gate<<<64, 256, 0, stream>>>(xbuf, gwt, gb, p);
  k_main<<<1024, 512, 0, stream>>>(xbuf, pwt, p, pb, out);
}

// Round 7
// 148.730 us; speedup vs baseline: 1.0273x; 1.0273x over previous
//
#include <hip/hip_runtime.h>
#include <cstdint>
#include <cstddef>

// SoftTree: out[b,o] = sum_l ((x@pw[o])[b,l] + pb[o,l]) * p[b,l]
// B=4096, I=512, O=64, L=256, GATES=255, depth 8.
#define GATES 255

typedef __attribute__((ext_vector_type(8))) short bf16x8;   // 8 bf16 = 4 VGPR
typedef __attribute__((ext_vector_type(4))) float f32x4;

__device__ __forceinline__ short f2bf(float f) {
  union { float f; uint32_t u; } c; c.f = f;
  uint32_t r = c.u + 0x7FFFu + ((c.u >> 16) & 1u);   // RNE
  return (short)(r >> 16);
}

#define GLOAD16(gp, lp) __builtin_amdgcn_global_load_lds( \
    (const __attribute__((address_space(1))) uint32_t*)(gp), \
    (__attribute__((address_space(3))) uint32_t*)(lp), 16, 0, 0)

// ---------------- merged prep: x->bf16 | gw transpose | pw transpose ---------
__global__ __launch_bounds__(256) void k_prep(const float* __restrict__ x,
                                              short* __restrict__ xb,
                                              const float* __restrict__ gw,
                                              short* __restrict__ gwt,
                                              const float* __restrict__ pw,
                                              short* __restrict__ pwt) {
  __shared__ short t[64][65];
  const int bx = blockIdx.x;
  const int tid = threadIdx.x;

  if (bx < 2048) {                      // ---- convert x ----
    const int i = bx * 256 + tid;       // 524288 float4s
    const float4 v = ((const float4*)x)[i];
    short4 s;
    s.x = f2bf(v.x); s.y = f2bf(v.y); s.z = f2bf(v.z); s.w = f2bf(v.w);
    ((short4*)xb)[i] = s;
    return;
  }

  const int c = tid & 63, r0 = tid >> 6;

  if (bx < 2080) {                      // ---- gw transpose ----
    const int b2 = bx - 2048;           // 8 iblk * 4 gblk
    const int ib = b2 >> 2, gb = b2 & 3;
    const int i0 = ib << 6, g0 = gb << 6;
#pragma unroll
    for (int rr = 0; rr < 16; ++rr) {
      const int i = rr * 4 + r0;
      const int g = g0 + c;
      t[i][c] = (g < GATES) ? f2bf(gw[(size_t)(i0 + i) * GATES + g]) : (short)0;
    }
    __syncthreads();
#pragma unroll
    for (int rr = 0; rr < 16; ++rr) {
      const int gg = rr * 4 + r0;
      gwt[(size_t)(g0 + gg) * 512 + i0 + c] = t[c][gg];
    }
    return;
  }

  // ---- pw transpose ----
  const int b2 = bx - 2080;             // 64 o * 8 iblk * 4 lblk
  const int o = b2 >> 5;
  const int ib = (b2 >> 2) & 7;
  const int lb = b2 & 3;
  const int i0 = ib << 6, l0 = lb << 6;
  const float* src = pw + ((size_t)o * 512 + i0) * 256 + l0;
#pragma unroll
  for (int rr = 0; rr < 16; ++rr) {
    const int i = rr * 4 + r0;
    t[i][c] = f2bf(src[(size_t)i * 256 + c]);            // coalesced over l
  }
  __syncthreads();
  short* dst = pwt + ((size_t)o * 256 + l0) * 512 + i0;
#pragma unroll
  for (int rr = 0; rr < 16; ++rr) {
    const int ll = rr * 4 + r0;
    dst[(size_t)ll * 512 + c] = t[c][ll];                // coalesced over i
  }
}

// ---------------- gating via MFMA + fused sigmoid + leaf products ------------
__global__ __launch_bounds__(256, 1) void k_gate(const short* __restrict__ xb,
                                                 const short* __restrict__ gwt,
                                                 const float* __restrict__ gb,
                                                 float* __restrict__ p) {
  __shared__ short a_lds[64 * 64];     // 8KB
  __shared__ short b_lds[256 * 64];    // 32KB
  __shared__ float gs[64][260];        // sigmoid gates, 65KB

  const int b0 = blockIdx.x << 6;      // 64 blocks
  const int tid = threadIdx.x;
  const int lane = tid & 63;
  const int w = tid >> 6;
  const int wr = w >> 1, wc = w & 1;   // wave tile 32x128

  const short* Ab = xb + (size_t)b0 * 512;

  f32x4 acc[2][8];
#pragma unroll
  for (int mf = 0; mf < 2; ++mf)
#pragma unroll
    for (int nf = 0; nf < 8; ++nf) {
      acc[mf][nf][0] = 0.f; acc[mf][nf][1] = 0.f;
      acc[mf][nf][2] = 0.f; acc[mf][nf][3] = 0.f;
    }

  for (int s = 0; s < 8; ++s) {
    const int i0 = s << 6;
    __syncthreads();
#pragma unroll
    for (int sw = 0; sw < 2; ++sw) {   // A: 512 x 16B chunks
      const int chunk = sw * 256 + tid;
      const int r = chunk >> 3, c = (chunk & 7) << 3;
      GLOAD16(Ab + (size_t)r * 512 + i0 + c, a_lds + chunk * 8);
    }
#pragma unroll
    for (int sw = 0; sw < 8; ++sw) {   // B: 2048 x 16B chunks
      const int chunk = sw * 256 + tid;
      const int r = chunk >> 3, c = (chunk & 7) << 3;
      GLOAD16(gwt + (size_t)r * 512 + i0 + c, b_lds + chunk * 8);
    }
    __syncthreads();
#pragma unroll
    for (int kk = 0; kk < 2; ++kk) {
      const int kb = (kk << 5) + ((lane >> 4) << 3);
      bf16x8 af[2], bfr[8];
#pragma unroll
      for (int mf = 0; mf < 2; ++mf) {
        const int row = (wr << 5) + (mf << 4) + (lane & 15);
        af[mf] = *(const bf16x8*)(a_lds + row * 64 + kb);
      }
#pragma unroll
      for (int nf = 0; nf < 8; ++nf) {
        const int row = (wc << 7) + (nf << 4) + (lane & 15);
        bfr[nf] = *(const bf16x8*)(b_lds + row * 64 + kb);
      }
#pragma unroll
      for (int mf = 0; mf < 2; ++mf)
#pragma unroll
        for (int nf = 0; nf < 8; ++nf)
          acc[mf][nf] = __builtin_amdgcn_mfma_f32_16x16x32_bf16(
              af[mf], bfr[nf], acc[mf][nf], 0, 0, 0);
    }
  }

  // sigmoid(logit + gb) -> gs[b_local][g]
  const int grp = lane >> 4, lcol = lane & 15;
#pragma unroll
  for (int nf = 0; nf < 8; ++nf) {
    const int g = (wc << 7) + (nf << 4) + lcol;
    const float bias = (g < GATES) ? gb[g] : 0.f;
#pragma unroll
    for (int mf = 0; mf < 2; ++mf)
#pragma unroll
      for (int rg = 0; rg < 4; ++rg) {
        const int bl = (wr << 5) + (mf << 4) + (grp << 2) + rg;
        const float z = acc[mf][nf][rg] + bias;
        gs[bl][g] = 1.f / (1.f + __expf(-z));
      }
  }
  __syncthreads();

  // leaf probs: thread handles leaf l=tid for all 64 rows
  const int l = tid;
  for (int r = 0; r < 64; ++r) {
    float prob = 1.f;
    int index = 1;
#pragma unroll
    for (int j = 0; j < 8; ++j) {
      const int bit = (l >> (7 - j)) & 1;
      const float gg = gs[r][index - 1];
      prob *= bit ? (1.f - gg) : gg;
      index = 2 * index + bit;
    }
    p[(size_t)(b0 + r) * 256 + l] = prob;
  }
}

// ---------------- main fused GEMM: block = (bm-tile, o-chunk of 4) ----------
// BM=256, BN=256(=L), BK=64; 8 waves 2Mx4N; 8-phase counted-vmcnt pipeline
// runs CONTINUOUSLY over 32 tiles (4 o x 8 kt); per-o epilogue drains once.
// Traffic theory (R6 post-mortem): R3-R6 plateau = 768MB/dispatch through the
// L3 path (A+B staging + p gather) at ~6.2 TB/s. Grid 16bm x 16oc (1/CU):
// per XCD (bid%8 RR, bm=bid&15) resident = 2 bm -> A-tiles (512KB) and
// p-slices (512KB) are L2-RESIDENT; their restages/gathers hit L2. Only B
// (pwt) streams from L3 (~130-260MB). Expect ~2.5-3x less L3 traffic.
__global__ __launch_bounds__(512, 1) void k_main(const short* __restrict__ xb,
                                                 const short* __restrict__ pwt,
                                                 const float* __restrict__ p,
                                                 const float* __restrict__ pb,
                                                 float* __restrict__ out) {
  __shared__ short lds[65536];        // [buf][mat][kh][256*32] = 128KB
  __shared__ float red[4][256];       // epilogue cross-wave combine, 4KB

  const int bx = blockIdx.x;          // 256 blocks: bm = bx&15, oc = bx>>4
  const int bm0 = (bx & 15) << 8;
  const int oc = bx >> 4;             // o = oc*4 + (tt>>3)
  const int tid = threadIdx.x;
  const int lane = tid & 63;
  const int w = tid >> 6;             // 0..7
  const int wr = w >> 2;              // 0..1  (m half)
  const int wc = w & 3;               // 0..3  (n quarter)

  const short* Ab = xb + (size_t)bm0 * 512;
  const short* Bo = pwt + (size_t)oc * 4 * 131072;   // o-chunk base

  f32x4 acc[8][4];
#pragma unroll
  for (int mf = 0; mf < 8; ++mf)
#pragma unroll
    for (int nf = 0; nf < 4; ++nf) {
      acc[mf][nf][0] = 0.f; acc[mf][nf][1] = 0.f;
      acc[mf][nf][2] = 0.f; acc[mf][nf][3] = 0.f;
    }

  // half s of global tile tt (tt = oi*8 + kt): s = {A-kh0,B-kh0,A-kh1,B-kh1}.
  // LDS pos pp in row receives global 16B-block pp ^ ((row>>1)&3)  (T2).
  auto stageHalf = [&](int buf, int tt, int s) {
    const int mat = s & 1, kh = s >> 1;
    const short* base = mat ? (Bo + (size_t)(tt >> 3) * 131072) : Ab;
    const int koff = ((tt & 7) << 6) + (kh << 5);
    short* dst = &lds[((buf * 2 + mat) * 2 + kh) * 8192];
#pragma unroll
    for (int j = 0; j < 2; ++j) {
      const int c = j * 512 + tid;
      const int row = c >> 2, pp = c & 3;
      const int gblk = pp ^ ((row >> 1) & 3);
      GLOAD16(base + (size_t)row * 512 + koff + (gblk << 3), dst + c * 8);
    }
  };

  auto readB4 = [&](int buf, int kh, bf16x8 bfr[4]) {
    const short* src = &lds[((buf * 2 + 1) * 2 + kh) * 8192];
#pragma unroll
    for (int nf = 0; nf < 4; ++nf) {
      const int row = (wc << 6) + (nf << 4) + (lane & 15);
      const int blk = (lane >> 4) ^ ((row >> 1) & 3);
      bfr[nf] = *(const bf16x8*)(src + row * 32 + (blk << 3));
    }
  };
  auto readA4 = [&](int buf, int kh, int mh, bf16x8 af[4]) {
    const short* src = &lds[((buf * 2 + 0) * 2 + kh) * 8192];
#pragma unroll
    for (int mf = 0; mf < 4; ++mf) {
      const int row = (wr << 7) + (((mh << 2) + mf) << 4) + (lane & 15);
      const int blk = (lane >> 4) ^ ((row >> 1) & 3);
      af[mf] = *(const bf16x8*)(src + row * 32 + (blk << 3));
    }
  };
  auto mfma16 = [&](int mh, const bf16x8 af[4], const bf16x8 bfr[4]) {
    __builtin_amdgcn_s_setprio(1);
#pragma unroll
    for (int mf = 0; mf < 4; ++mf)
#pragma unroll
      for (int nf = 0; nf < 4; ++nf)
        acc[(mh << 2) + mf][nf] = __builtin_amdgcn_mfma_f32_16x16x32_bf16(
            af[mf], bfr[nf], acc[(mh << 2) + mf][nf], 0, 0, 0);
    __builtin_amdgcn_s_setprio(0);
  };

  // out[bm0..+255][o] = reduce(acc, p) + pb.p ; then re-zero acc.
  // Safe wrt counted-vmcnt: the p-load consumption (and __syncthreads)
  // drains vmcnt to 0; the steady vmcnt(4) pattern re-establishes (see R6).
  auto epilogue = [&](int oi) {
    const int o = (oc << 2) + oi;
    const int grp = lane >> 4;
    const int lcol = lane & 15;
    float pbv[4];
#pragma unroll
    for (int nf = 0; nf < 4; ++nf)
      pbv[nf] = pb[(size_t)o * 256 + (wc << 6) + (nf << 4) + lcol];
#pragma unroll
    for (int mf = 0; mf < 8; ++mf) {
#pragma unroll
      for (int rg = 0; rg < 4; ++rg) {
        const int bl = (wr << 7) + (mf << 4) + (grp << 2) + rg;
        const int b = bm0 + bl;
        float v = 0.f;
#pragma unroll
        for (int nf = 0; nf < 4; ++nf) {
          const int l = (wc << 6) + (nf << 4) + lcol;
          v += (acc[mf][nf][rg] + pbv[nf]) * p[(size_t)b * 256 + l];
        }
        v += __shfl_xor(v, 1);
        v += __shfl_xor(v, 2);
        v += __shfl_xor(v, 4);
        v += __shfl_xor(v, 8);
        if (lcol == 0) red[wc][bl] = v;
      }
    }
    __syncthreads();
    if (tid < 256)
      out[(size_t)(bm0 + tid) * 64 + o] =
          red[0][tid] + red[1][tid] + red[2][tid] + red[3][tid];
    __syncthreads();
#pragma unroll
    for (int mf = 0; mf < 8; ++mf)
#pragma unroll
      for (int nf = 0; nf < 4; ++nf) {
        acc[mf][nf][0] = 0.f; acc[mf][nf][1] = 0.f;
        acc[mf][nf][2] = 0.f; acc[mf][nf][3] = 0.f;
      }
  };

  bf16x8 af[4], bfr[4];

  // prologue: stage all 4 halves of tile 0, drain kh0's (oldest 4), barrier
  stageHalf(0, 0, 0); stageHalf(0, 0, 1); stageHalf(0, 0, 2); stageHalf(0, 0, 3);
  asm volatile("s_waitcnt vmcnt(4)" ::: "memory");
  __builtin_amdgcn_s_barrier();

  for (int t = 0; t < 31; ++t) {
    const int buf = t & 1;
    // ---- kh0, phase 0 (mh0) ----
    readB4(buf, 0, bfr); readA4(buf, 0, 0, af);
    stageHalf(buf ^ 1, t + 1, 0);
    __builtin_amdgcn_s_barrier();
    mfma16(0, af, bfr);
    __builtin_amdgcn_s_barrier();
    // ---- kh0, phase 1 (mh1) ----
    readA4(buf, 0, 1, af);
    stageHalf(buf ^ 1, t + 1, 1);
    __builtin_amdgcn_s_barrier();
    mfma16(1, af, bfr);
    asm volatile("s_waitcnt vmcnt(4)" ::: "memory");   // drain this-tile kh1
    __builtin_amdgcn_s_barrier();
    // ---- kh1, phase 2 (mh0) ----
    readB4(buf, 1, bfr); readA4(buf, 1, 0, af);
    stageHalf(buf ^ 1, t + 1, 2);
    __builtin_amdgcn_s_barrier();
    mfma16(0, af, bfr);
    __builtin_amdgcn_s_barrier();
    // ---- kh1, phase 3 (mh1) ----
    readA4(buf, 1, 1, af);
    stageHalf(buf ^ 1, t + 1, 3);
    __builtin_amdgcn_s_barrier();
    mfma16(1, af, bfr);
    asm volatile("s_waitcnt vmcnt(4)" ::: "memory");   // drain next-tile kh0
    __builtin_amdgcn_s_barrier();
    if ((t & 7) == 7) epilogue(t >> 3);                // t = 7, 15, 23
  }
  // ---- tile 31 (buf=1), no staging ----
  readB4(1, 0, bfr); readA4(1, 0, 0, af);
  __builtin_amdgcn_s_barrier();
  mfma16(0, af, bfr);
  __builtin_amdgcn_s_barrier();
  readA4(1, 0, 1, af);
  __builtin_amdgcn_s_barrier();
  mfma16(1, af, bfr);
  asm volatile("s_waitcnt vmcnt(0)" ::: "memory");     // drain tile-31 kh1
  __builtin_amdgcn_s_barrier();
  readB4(1, 1, bfr); readA4(1, 1, 0, af);
  __builtin_amdgcn_s_barrier();
  mfma16(0, af, bfr);
  __builtin_amdgcn_s_barrier();
  readA4(1, 1, 1, af);
  __builtin_amdgcn_s_barrier();
  mfma16(1, af, bfr);
  __builtin_amdgcn_s_barrier();
  epilogue(3);
}

extern "C" void kernel_launch(void* const* d_in, const int* in_sizes, int n_in,
                              void* d_out, int out_size, void* d_ws, size_t ws_size,
                              hipStream_t stream) {
  (void)in_sizes; (void)n_in; (void)out_size; (void)ws_size;
  const float* x  = (const float*)d_in[0];
  const float* gw = (const float*)d_in[1];
  const float* gb = (const float*)d_in[2];
  const float* pw = (const float*)d_in[3];
  const float* pb = (const float*)d_in[4];
  // d_in[5] leaf_idx / d_in[6] leaf_bit: tree is deterministic, recomputed in-kernel.
  float* out = (float*)d_out;

  char* ws = (char*)d_ws;
  short* xbuf = (short*)(ws);                              // 4 MB bf16 x
  short* gwt  = (short*)(ws + ((size_t)4 << 20));          // 256 KB bf16 gw_t
  short* pwt  = (short*)(ws + ((size_t)4 << 20) + (256 << 10));  // 16 MB bf16 pw_t
  float* p    = (float*)(ws + ((size_t)20 << 20) + (256 << 10)); // 4 MB leaf probs

  k_prep<<<4128, 256, 0, stream>>>(x, xbuf, gw, gwt, pw, pwt);
  k_gate<<<64, 256, 0, stream>>>(xbuf, gwt, gb, p);
  k_main<<<256, 512, 0, stream>>>(xbuf, pwt, p, pb, out);
}

// Round 8
// 119.331 us; speedup vs baseline: 1.2804x; 1.2464x over previous
//
#include <hip/hip_runtime.h>
#include <cstdint>
#include <cstddef>

// SoftTree: out[b,o] = sum_l ((x@pw[o])[b,l] + pb[o,l]) * p[b,l]
// B=4096, I=512, O=64, L=256, GATES=255, depth 8.
#define GATES 255

typedef __attribute__((ext_vector_type(8))) short bf16x8;   // 8 bf16 = 4 VGPR
typedef __attribute__((ext_vector_type(4))) float f32x4;

__device__ __forceinline__ short f2bf(float f) {
  union { float f; uint32_t u; } c; c.f = f;
  uint32_t r = c.u + 0x7FFFu + ((c.u >> 16) & 1u);   // RNE
  return (short)(r >> 16);
}

#define GLOAD16(gp, lp) __builtin_amdgcn_global_load_lds( \
    (const __attribute__((address_space(1))) uint32_t*)(gp), \
    (__attribute__((address_space(3))) uint32_t*)(lp), 16, 0, 0)

// ---------------- merged prep: x->bf16 | gw transpose | pw transpose ---------
__global__ __launch_bounds__(256) void k_prep(const float* __restrict__ x,
                                              short* __restrict__ xb,
                                              const float* __restrict__ gw,
                                              short* __restrict__ gwt,
                                              const float* __restrict__ pw,
                                              short* __restrict__ pwt) {
  __shared__ short t[64][65];
  const int bx = blockIdx.x;
  const int tid = threadIdx.x;

  if (bx < 2048) {                      // ---- convert x ----
    const int i = bx * 256 + tid;       // 524288 float4s
    const float4 v = ((const float4*)x)[i];
    short4 s;
    s.x = f2bf(v.x); s.y = f2bf(v.y); s.z = f2bf(v.z); s.w = f2bf(v.w);
    ((short4*)xb)[i] = s;
    return;
  }

  const int c = tid & 63, r0 = tid >> 6;

  if (bx < 2080) {                      // ---- gw transpose ----
    const int b2 = bx - 2048;           // 8 iblk * 4 gblk
    const int ib = b2 >> 2, gb = b2 & 3;
    const int i0 = ib << 6, g0 = gb << 6;
#pragma unroll
    for (int rr = 0; rr < 16; ++rr) {
      const int i = rr * 4 + r0;
      const int g = g0 + c;
      t[i][c] = (g < GATES) ? f2bf(gw[(size_t)(i0 + i) * GATES + g]) : (short)0;
    }
    __syncthreads();
#pragma unroll
    for (int rr = 0; rr < 16; ++rr) {
      const int gg = rr * 4 + r0;
      gwt[(size_t)(g0 + gg) * 512 + i0 + c] = t[c][gg];
    }
    return;
  }

  // ---- pw transpose ----
  const int b2 = bx - 2080;             // 64 o * 8 iblk * 4 lblk
  const int o = b2 >> 5;
  const int ib = (b2 >> 2) & 7;
  const int lb = b2 & 3;
  const int i0 = ib << 6, l0 = lb << 6;
  const float* src = pw + ((size_t)o * 512 + i0) * 256 + l0;
#pragma unroll
  for (int rr = 0; rr < 16; ++rr) {
    const int i = rr * 4 + r0;
    t[i][c] = f2bf(src[(size_t)i * 256 + c]);            // coalesced over l
  }
  __syncthreads();
  short* dst = pwt + ((size_t)o * 256 + l0) * 512 + i0;
#pragma unroll
  for (int rr = 0; rr < 16; ++rr) {
    const int ll = rr * 4 + r0;
    dst[(size_t)ll * 512 + c] = t[c][ll];                // coalesced over i
  }
}

// ---------------- gating via MFMA + fused sigmoid + leaf products ------------
__global__ __launch_bounds__(256, 1) void k_gate(const short* __restrict__ xb,
                                                 const short* __restrict__ gwt,
                                                 const float* __restrict__ gb,
                                                 float* __restrict__ p) {
  __shared__ short a_lds[64 * 64];     // 8KB
  __shared__ short b_lds[256 * 64];    // 32KB
  __shared__ float gs[64][260];        // sigmoid gates, 65KB

  const int b0 = blockIdx.x << 6;      // 64 blocks
  const int tid = threadIdx.x;
  const int lane = tid & 63;
  const int w = tid >> 6;
  const int wr = w >> 1, wc = w & 1;   // wave tile 32x128

  const short* Ab = xb + (size_t)b0 * 512;

  f32x4 acc[2][8];
#pragma unroll
  for (int mf = 0; mf < 2; ++mf)
#pragma unroll
    for (int nf = 0; nf < 8; ++nf) {
      acc[mf][nf][0] = 0.f; acc[mf][nf][1] = 0.f;
      acc[mf][nf][2] = 0.f; acc[mf][nf][3] = 0.f;
    }

  for (int s = 0; s < 8; ++s) {
    const int i0 = s << 6;
    __syncthreads();
#pragma unroll
    for (int sw = 0; sw < 2; ++sw) {   // A: 512 x 16B chunks
      const int chunk = sw * 256 + tid;
      const int r = chunk >> 3, c = (chunk & 7) << 3;
      GLOAD16(Ab + (size_t)r * 512 + i0 + c, a_lds + chunk * 8);
    }
#pragma unroll
    for (int sw = 0; sw < 8; ++sw) {   // B: 2048 x 16B chunks
      const int chunk = sw * 256 + tid;
      const int r = chunk >> 3, c = (chunk & 7) << 3;
      GLOAD16(gwt + (size_t)r * 512 + i0 + c, b_lds + chunk * 8);
    }
    __syncthreads();
#pragma unroll
    for (int kk = 0; kk < 2; ++kk) {
      const int kb = (kk << 5) + ((lane >> 4) << 3);
      bf16x8 af[2], bfr[8];
#pragma unroll
      for (int mf = 0; mf < 2; ++mf) {
        const int row = (wr << 5) + (mf << 4) + (lane & 15);
        af[mf] = *(const bf16x8*)(a_lds + row * 64 + kb);
      }
#pragma unroll
      for (int nf = 0; nf < 8; ++nf) {
        const int row = (wc << 7) + (nf << 4) + (lane & 15);
        bfr[nf] = *(const bf16x8*)(b_lds + row * 64 + kb);
      }
#pragma unroll
      for (int mf = 0; mf < 2; ++mf)
#pragma unroll
        for (int nf = 0; nf < 8; ++nf)
          acc[mf][nf] = __builtin_amdgcn_mfma_f32_16x16x32_bf16(
              af[mf], bfr[nf], acc[mf][nf], 0, 0, 0);
    }
  }

  // sigmoid(logit + gb) -> gs[b_local][g]
  const int grp = lane >> 4, lcol = lane & 15;
#pragma unroll
  for (int nf = 0; nf < 8; ++nf) {
    const int g = (wc << 7) + (nf << 4) + lcol;
    const float bias = (g < GATES) ? gb[g] : 0.f;
#pragma unroll
    for (int mf = 0; mf < 2; ++mf)
#pragma unroll
      for (int rg = 0; rg < 4; ++rg) {
        const int bl = (wr << 5) + (mf << 4) + (grp << 2) + rg;
        const float z = acc[mf][nf][rg] + bias;
        gs[bl][g] = 1.f / (1.f + __expf(-z));
      }
  }
  __syncthreads();

  // leaf probs: thread handles leaf l=tid for all 64 rows
  const int l = tid;
  for (int r = 0; r < 64; ++r) {
    float prob = 1.f;
    int index = 1;
#pragma unroll
    for (int j = 0; j < 8; ++j) {
      const int bit = (l >> (7 - j)) & 1;
      const float gg = gs[r][index - 1];
      prob *= bit ? (1.f - gg) : gg;
      index = 2 * index + bit;
    }
    p[(size_t)(b0 + r) * 256 + l] = prob;
  }
}

// ---------------- main fused GEMM (R3 structure + T2 swizzle + 48KB LDS) ----
// BM=128, BN=256(=L), BK=64; 4 waves 2x2; wave tile 64x128. 2-barrier loop.
// Occupancy theory (R7 post-mortem): R3 (2 blocks/CU) beat all 1-block/CU
// variants -- inter-block overlap (m114) hides the barrier drain. LDS trimmed
// to exactly 48KB (red[] overlays a_lds) so 3 blocks/CU can fit; R3's 49KB
// rounded past the granule and capped at 2.
// T2 both-sides swizzle (G4 attn case): 128B-row b128 reads are 16-way
// conflicts (R3: 1.9e7 = 29% of cycles). LDS block pp holds global block
// pp^(row&7) (inverse-swizzled source, linear gload dest, rule #21); reads
// XOR the same term -> spread across 8 16B slots.
__global__ __launch_bounds__(256, 2) void k_main(const short* __restrict__ xb,
                                                 const short* __restrict__ pwt,
                                                 const float* __restrict__ p,
                                                 const float* __restrict__ pb,
                                                 float* __restrict__ out) {
  __shared__ short a_lds[128 * 64];   // 16KB
  __shared__ short b_lds[256 * 64];   // 32KB; total 48KB exactly

  const int bx = blockIdx.x;          // 64 o * 32 bm = 2048; o-major
  const int o = bx >> 5;
  const int bm0 = (bx & 31) << 7;
  const int tid = threadIdx.x;
  const int lane = tid & 63;
  const int w = tid >> 6;
  const int wr = w >> 1;              // wave row (m): 0..1
  const int wc = w & 1;               // wave col (n): 0..1

  const short* Ab = xb + (size_t)bm0 * 512;
  const short* Bb = pwt + (size_t)o * (256 * 512);

  f32x4 acc[4][8];
#pragma unroll
  for (int mf = 0; mf < 4; ++mf)
#pragma unroll
    for (int nf = 0; nf < 8; ++nf) {
      acc[mf][nf][0] = 0.f; acc[mf][nf][1] = 0.f;
      acc[mf][nf][2] = 0.f; acc[mf][nf][3] = 0.f;
    }

  for (int s = 0; s < 8; ++s) {       // K = 8 stages of 64
    const int i0 = s << 6;
    __syncthreads();                  // previous compute done before overwrite
#pragma unroll
    for (int sw = 0; sw < 4; ++sw) {  // A: 1024 x 16B chunks
      const int c = sw * 256 + tid;
      const int r = c >> 3;
      const int gblk = (c & 7) ^ (r & 7);          // inverse-swizzled source
      GLOAD16(Ab + (size_t)r * 512 + i0 + (gblk << 3), a_lds + c * 8);
    }
#pragma unroll
    for (int sw = 0; sw < 8; ++sw) {  // B: 2048 x 16B chunks
      const int c = sw * 256 + tid;
      const int r = c >> 3;
      const int gblk = (c & 7) ^ (r & 7);
      GLOAD16(Bb + (size_t)r * 512 + i0 + (gblk << 3), b_lds + c * 8);
    }
    __syncthreads();                  // vmcnt(0) drained by compiler
#pragma unroll
    for (int kk = 0; kk < 2; ++kk) {
      const int kblk = (kk << 2) + (lane >> 4);    // 16B block 0..7
      bf16x8 af[4], bfr[8];
#pragma unroll
      for (int mf = 0; mf < 4; ++mf) {
        const int row = (wr << 6) + (mf << 4) + (lane & 15);
        af[mf] = *(const bf16x8*)(a_lds + row * 64 + ((kblk ^ (row & 7)) << 3));
      }
#pragma unroll
      for (int nf = 0; nf < 8; ++nf) {
        const int row = (wc << 7) + (nf << 4) + (lane & 15);
        bfr[nf] = *(const bf16x8*)(b_lds + row * 64 + ((kblk ^ (row & 7)) << 3));
      }
#pragma unroll
      for (int mf = 0; mf < 4; ++mf)
#pragma unroll
        for (int nf = 0; nf < 8; ++nf)
          acc[mf][nf] = __builtin_amdgcn_mfma_f32_16x16x32_bf16(
              af[mf], bfr[nf], acc[mf][nf], 0, 0, 0);
    }
  }

  // epilogue: D lane map (m89): col(l)=lane&15, row(b)=(lane>>4)*4+reg
  __syncthreads();                    // K-loop reads done; reuse a_lds as red[]
  float* red = (float*)a_lds;         // red[2][128] overlay, 1KB
  const int grp = lane >> 4;
  const int lcol = lane & 15;
  float pbv[8];
#pragma unroll
  for (int nf = 0; nf < 8; ++nf)
    pbv[nf] = pb[(size_t)o * 256 + (wc << 7) + (nf << 4) + lcol];
#pragma unroll
  for (int mf = 0; mf < 4; ++mf) {
#pragma unroll
    for (int rg = 0; rg < 4; ++rg) {
      const int bl = (wr << 6) + (mf << 4) + (grp << 2) + rg;  // b within tile
      const int b = bm0 + bl;
      float v = 0.f;
#pragma unroll
      for (int nf = 0; nf < 8; ++nf) {
        const int l = (wc << 7) + (nf << 4) + lcol;
        v += (acc[mf][nf][rg] + pbv[nf]) * p[(size_t)b * 256 + l];
      }
      // reduce over the 16 lanes (same b, different l residues)
      v += __shfl_xor(v, 1);
      v += __shfl_xor(v, 2);
      v += __shfl_xor(v, 4);
      v += __shfl_xor(v, 8);
      if (lcol == 0) red[wc * 128 + bl] = v;
    }
  }
  __syncthreads();
  if (tid < 128) {
    out[(size_t)(bm0 + tid) * 64 + o] = red[tid] + red[128 + tid];
  }
}

extern "C" void kernel_launch(void* const* d_in, const int* in_sizes, int n_in,
                              void* d_out, int out_size, void* d_ws, size_t ws_size,
                              hipStream_t stream) {
  (void)in_sizes; (void)n_in; (void)out_size; (void)ws_size;
  const float* x  = (const float*)d_in[0];
  const float* gw = (const float*)d_in[1];
  const float* gb = (const float*)d_in[2];
  const float* pw = (const float*)d_in[3];
  const float* pb = (const float*)d_in[4];
  // d_in[5] leaf_idx / d_in[6] leaf_bit: tree is deterministic, recomputed in-kernel.
  float* out = (float*)d_out;

  char* ws = (char*)d_ws;
  short* xbuf = (short*)(ws);                              // 4 MB bf16 x
  short* gwt  = (short*)(ws + ((size_t)4 << 20));          // 256 KB bf16 gw_t
  short* pwt  = (short*)(ws + ((size_t)4 << 20) + (256 << 10));  // 16 MB bf16 pw_t
  float* p    = (float*)(ws + ((size_t)20 << 20) + (256 << 10)); // 4 MB leaf probs

  k_prep<<<4128, 256, 0, stream>>>(x, xbuf, gw, gwt, pw, pwt);
  k_gate<<<64, 256, 0, stream>>>(xbuf, gwt, gb, p);
  k_main<<<2048, 256, 0, stream>>>(xbuf, pwt, p, pb, out);
}